// Round 10
// baseline (688.483 us; speedup 1.0000x reference)
//
#include <hip/hip_runtime.h>
#include <cstddef>
#include <cstdint>

#define B_    4
#define T_    1024
#define F_    128
#define D_    512
#define H_    8
#define L_    4
#define DFF_  2048
#define HD_   64
#define SCALE_ 0.125f   // 1/sqrt(64)
#define LOG2E_ 1.4426950408889634f
#define CL2E_  (SCALE_ * LOG2E_)

typedef __attribute__((ext_vector_type(8))) short bf16x8;
typedef __attribute__((ext_vector_type(4))) float f32x4;

#define AS1(p) ((const __attribute__((address_space(1))) void*)(p))
#define AS3(p) ((__attribute__((address_space(3))) void*)(p))

__device__ __forceinline__ short f2bf(float f) {
    unsigned u = __float_as_uint(f);
    u += 0x7FFFu + ((u >> 16) & 1u);      // round-to-nearest-even
    return (short)(u >> 16);
}
__device__ __forceinline__ float bf2f(short s) {
    return __uint_as_float(((unsigned)(unsigned short)s) << 16);
}

// ---------------------------------------------------------------------------
// LayerNorm, fp32 in -> bf16 out
// ---------------------------------------------------------------------------
__global__ __launch_bounds__(256) void ln_k(
    const float* __restrict__ X, const float* __restrict__ w,
    const float* __restrict__ b, short* __restrict__ Y)
{
    const int row = blockIdx.x;
    const int tid = threadIdx.x;
    const float* xr = X + (size_t)row * D_;
    const float v0 = xr[tid];
    const float v1 = xr[tid + 256];
    float s  = v0 + v1;
    float s2 = v0 * v0 + v1 * v1;
#pragma unroll
    for (int off = 1; off < 64; off <<= 1) {
        s  += __shfl_xor(s,  off);
        s2 += __shfl_xor(s2, off);
    }
    __shared__ float ss[4], ss2[4];
    if ((tid & 63) == 0) { ss[tid >> 6] = s; ss2[tid >> 6] = s2; }
    __syncthreads();
    s  = ss[0]  + ss[1]  + ss[2]  + ss[3];
    s2 = ss2[0] + ss2[1] + ss2[2] + ss2[3];
    const float mean = s * (1.f / D_);
    const float var  = s2 * (1.f / D_) - mean * mean;
    const float r    = rsqrtf(var + 1e-5f);
    short* yr = Y + (size_t)row * D_;
    yr[tid]       = f2bf((v0 - mean) * r * w[tid]       + b[tid]);
    yr[tid + 256] = f2bf((v1 - mean) * r * w[tid + 256] + b[tid + 256]);
}

// ---------------------------------------------------------------------------
// Merged prep: weight transposes + bias quant + nf cast + qkv bias fuse.
// Block ranges (all tile counts exact, no early exit):
//   [0,3072)      qkv transposes   (id = bid>>8, tile = bid&255)      512x512
//   [3072,4096)   oW transposes                                        512x512
//   [4096,8192)   f1W transposes   (1024 tiles each)                   512x2048
//   [8192,12288)  f2W transposes                                       2048x512
//   [12288,12352) node_W transpose (64 tiles)                          128x512
//   [12352,16448) attention-bias u8 quant (4096 blocks)
//   [16448,16960) nf -> bf16 cast (512 blocks)
//   [16960,16984) fused qkv bias (24 blocks)
// ---------------------------------------------------------------------------
__global__ __launch_bounds__(256) void prep_all_k(
    const float* __restrict__ qW, const float* __restrict__ kW,
    const float* __restrict__ vW, const float* __restrict__ oW,
    const float* __restrict__ f1W, const float* __restrict__ f2W,
    const float* __restrict__ nW,
    short* __restrict__ WqkvT, short* __restrict__ WoT,
    short* __restrict__ Wf1T, short* __restrict__ Wf2T,
    short* __restrict__ nWt,
    const int* __restrict__ et, const int* __restrict__ sp,
    const float* __restrict__ ee, const float* __restrict__ de,
    unsigned char* __restrict__ biasT8,
    const float* __restrict__ nf, short* __restrict__ nfb,
    const float* __restrict__ qb, const float* __restrict__ kb,
    const float* __restrict__ vb, float* __restrict__ biasf)
{
    const int bid = blockIdx.x;
    const int tid = threadIdx.x;

    if (bid < 12352) {
        // ---- transpose section
        const float* src; short* dst; int K, N, tile;
        if (bid < 3072) {
            const int id = bid >> 8, l = id / 3, which = id % 3;
            const float* s3 = (which == 0) ? qW : (which == 1) ? kW : vW;
            src = s3 + (size_t)l * D_ * D_;
            dst = WqkvT + ((size_t)l * 3 + which) * D_ * D_;
            K = D_; N = D_; tile = bid & 255;
        } else if (bid < 4096) {
            const int l = (bid - 3072) >> 8;
            src = oW + (size_t)l * D_ * D_;  dst = WoT + (size_t)l * D_ * D_;
            K = D_; N = D_; tile = (bid - 3072) & 255;
        } else if (bid < 8192) {
            const int l = (bid - 4096) >> 10;
            src = f1W + (size_t)l * D_ * DFF_;  dst = Wf1T + (size_t)l * DFF_ * D_;
            K = D_; N = DFF_; tile = (bid - 4096) & 1023;
        } else if (bid < 12288) {
            const int l = (bid - 8192) >> 10;
            src = f2W + (size_t)l * DFF_ * D_;  dst = Wf2T + (size_t)l * D_ * DFF_;
            K = DFF_; N = D_; tile = (bid - 8192) & 1023;
        } else {
            src = nW; dst = nWt; K = F_; N = D_; tile = bid - 12288;
        }
        const int nt = N >> 5;
        const int k0 = (tile / nt) << 5, n0 = (tile % nt) << 5;
        __shared__ float t[32][33];
        const int c = tid & 31, r0 = tid >> 5;
#pragma unroll
        for (int i = 0; i < 32; i += 8)
            t[r0 + i][c] = src[(size_t)(k0 + r0 + i) * N + n0 + c];
        __syncthreads();
#pragma unroll
        for (int i = 0; i < 32; i += 8)
            dst[(size_t)(n0 + r0 + i) * K + k0 + c] = f2bf(t[c][r0 + i]);
        return;
    }

    if (bid >= 16448) {
        if (bid < 16960) {
            const int i = (((bid - 16448) << 8) + tid) << 2;
            const float4 v = *(const float4*)(nf + i);
            *(short4*)(nfb + i) =
                make_short4(f2bf(v.x), f2bf(v.y), f2bf(v.z), f2bf(v.w));
        } else {
            const int i = ((bid - 16960) << 8) + tid;
            const int l = i / 1536, c = i % 1536;
            float v;
            if (c < 512)       v = qb[l * 512 + c];
            else if (c < 1024) v = kb[l * 512 + c - 512];
            else               v = vb[l * 512 + c - 1024];
            biasf[i] = v;
        }
        return;
    }

    // ---- attention-bias u8 quant
    __shared__ float eeS[16][8], deS[21][8];
    if (tid < 128) eeS[tid >> 3][tid & 7] = ee[tid];
    for (int t2 = tid; t2 < 168; t2 += 256)
        deS[t2 >> 3][t2 & 7] = de[t2];
    __syncthreads();
    const int gid = (bid - 12352) * 256 + tid;   // over B*T*T/4
    const int j4  = (gid & 255) << 2;
    const int bi  = gid >> 8;                    // b*T + i
    const size_t base = (size_t)bi * T_ + j4;
    const int4 e = *(const int4*)(et + base);
    const int4 s = *(const int4*)(sp + base);
    const int b = bi >> 10, i = bi & 1023;
    const int ex[4] = {e.x, e.y, e.z, e.w};
    const int sx[4] = {min(s.x, 20), min(s.y, 20), min(s.z, 20), min(s.w, 20)};
#pragma unroll
    for (int h = 0; h < 8; ++h) {
        uchar4 o;
        float v;
        v = (eeS[ex[0]][h] + deS[sx[0]][h]) * LOG2E_ + 0.5f;
        o.x = (unsigned char)(int)fminf(fmaxf(v * 255.f + 0.5f, 0.f), 255.f);
        v = (eeS[ex[1]][h] + deS[sx[1]][h]) * LOG2E_ + 0.5f;
        o.y = (unsigned char)(int)fminf(fmaxf(v * 255.f + 0.5f, 0.f), 255.f);
        v = (eeS[ex[2]][h] + deS[sx[2]][h]) * LOG2E_ + 0.5f;
        o.z = (unsigned char)(int)fminf(fmaxf(v * 255.f + 0.5f, 0.f), 255.f);
        v = (eeS[ex[3]][h] + deS[sx[3]][h]) * LOG2E_ + 0.5f;
        o.w = (unsigned char)(int)fminf(fmaxf(v * 255.f + 0.5f, 0.f), 255.f);
        *(uchar4*)(biasT8 + ((size_t)((b * H_ + h) * T_ + i)) * T_ + j4) = o;
    }
}

// ---------------------------------------------------------------------------
// Embedding as MFMA GEMM, 128x64 tile, K=128
// ---------------------------------------------------------------------------
__global__ __launch_bounds__(256) void embed_mm_k(
    const short* __restrict__ A, const short* __restrict__ Wt,
    const float* __restrict__ nb, const float* __restrict__ cb,
    const float* __restrict__ cW, const float* __restrict__ cent,
    float* __restrict__ C)
{
    const int K = F_, N = D_;
    __shared__ short As[128 * 32];
    __shared__ short Bs[64 * 32];
    const int tid  = threadIdx.x;
    const int lane = tid & 63, wv = tid >> 6;
    const int bm = blockIdx.y << 7, bn = blockIdx.x << 6;
    const int wm = (wv & 1) << 6, wn = (wv >> 1) << 5;

    const int c0 = (wv << 6) + lane;
    const int m0 = c0 >> 2, q0 = (c0 & 3) ^ ((m0 >> 1) & 3);
    const int c1 = 256 + c0;
    const int m1 = c1 >> 2, q1 = (c1 & 3) ^ ((m1 >> 1) & 3);

    const short* gA0 = A  + (size_t)(bm + m0) * K + (q0 << 3);
    const short* gA1 = A  + (size_t)(bm + m1) * K + (q1 << 3);
    const short* gB0 = Wt + (size_t)(bn + m0) * K + (q0 << 3);

    f32x4 acc[4][2];
#pragma unroll
    for (int i = 0; i < 4; ++i)
#pragma unroll
        for (int j = 0; j < 2; ++j)
            acc[i][j] = (f32x4){0.f, 0.f, 0.f, 0.f};

    const int fm = lane & 15, fq = lane >> 4;
    int caddr[4], baddr[2];
#pragma unroll
    for (int t = 0; t < 4; ++t) {
        const int rowA = wm + (t << 4) + fm;
        caddr[t] = ((rowA << 2) + (fq ^ ((rowA >> 1) & 3))) << 3;
    }
#pragma unroll
    for (int t = 0; t < 2; ++t) {
        const int rowB = wn + (t << 4) + fm;
        baddr[t] = ((rowB << 2) + (fq ^ ((rowB >> 1) & 3))) << 3;
    }

    for (int k0 = 0; k0 < K; k0 += 32) {
        __builtin_amdgcn_global_load_lds(AS1(gA0), AS3(As + (wv << 9)),        16, 0, 0);
        __builtin_amdgcn_global_load_lds(AS1(gA1), AS3(As + 2048 + (wv << 9)), 16, 0, 0);
        __builtin_amdgcn_global_load_lds(AS1(gB0), AS3(Bs + (wv << 9)),        16, 0, 0);
        gA0 += 32; gA1 += 32; gB0 += 32;
        __syncthreads();

        bf16x8 af[4], bf[2];
#pragma unroll
        for (int t = 0; t < 4; ++t) af[t] = *(const bf16x8*)(As + caddr[t]);
#pragma unroll
        for (int t = 0; t < 2; ++t) bf[t] = *(const bf16x8*)(Bs + baddr[t]);
#pragma unroll
        for (int i = 0; i < 4; ++i)
#pragma unroll
            for (int j = 0; j < 2; ++j)
                acc[i][j] = __builtin_amdgcn_mfma_f32_16x16x32_bf16(
                    af[i], bf[j], acc[i][j], 0, 0, 0);
        __syncthreads();
    }

    const int col0 = bn + wn + fm;
    const int row0 = bm + wm + (fq << 2);
#pragma unroll
    for (int j = 0; j < 2; ++j) {
        const int colg = col0 + (j << 4);
        const float bb = nb[colg] + cb[colg];
        const float cw = cW[colg];
#pragma unroll
        for (int i = 0; i < 4; ++i) {
#pragma unroll
            for (int r = 0; r < 4; ++r) {
                const int rowg = row0 + (i << 4) + r;
                C[(size_t)rowg * N + colg] = acc[i][j][r] + bb + cent[rowg] * cw;
            }
        }
    }
}

// ---------------------------------------------------------------------------
// bf16 MFMA GEMM, 128x128 tile: C = act(A @ Wt^T + bias) (+R)
// OUTM: 0 fp32, 1 bf16.
// ---------------------------------------------------------------------------
template <int OUTM, int ACT, int RES>
__global__ __launch_bounds__(256) void mm_k(
    const short* __restrict__ A, const short* __restrict__ Wt,
    const float* __restrict__ bias, const float* __restrict__ R,
    void* __restrict__ Cv, int M, int N, int K)
{
    __shared__ short As[128 * 32];
    __shared__ short Bs[128 * 32];
    const int tid  = threadIdx.x;
    const int lane = tid & 63, wv = tid >> 6;
    const int bm = blockIdx.y << 7, bn = blockIdx.x << 7;
    const int wm = (wv & 1) << 6, wn = (wv >> 1) << 6;

    const int c0 = (wv << 6) + lane;
    const int m0 = c0 >> 2, q0 = (c0 & 3) ^ ((m0 >> 1) & 3);
    const int c1 = 256 + c0;
    const int m1 = c1 >> 2, q1 = (c1 & 3) ^ ((m1 >> 1) & 3);

    const short* gA0 = A  + (size_t)(bm + m0) * K + (q0 << 3);
    const short* gA1 = A  + (size_t)(bm + m1) * K + (q1 << 3);
    const short* gB0 = Wt + (size_t)(bn + m0) * K + (q0 << 3);
    const short* gB1 = Wt + (size_t)(bn + m1) * K + (q1 << 3);

    f32x4 acc[4][4];
#pragma unroll
    for (int i = 0; i < 4; ++i)
#pragma unroll
        for (int j = 0; j < 4; ++j)
            acc[i][j] = (f32x4){0.f, 0.f, 0.f, 0.f};

    const int fm = lane & 15, fq = lane >> 4;
    int caddr[4], baddr[4];
#pragma unroll
    for (int t = 0; t < 4; ++t) {
        const int rowA = wm + (t << 4) + fm;
        caddr[t] = ((rowA << 2) + (fq ^ ((rowA >> 1) & 3))) << 3;
        const int rowB = wn + (t << 4) + fm;
        baddr[t] = ((rowB << 2) + (fq ^ ((rowB >> 1) & 3))) << 3;
    }

    for (int k0 = 0; k0 < K; k0 += 32) {
        __builtin_amdgcn_global_load_lds(AS1(gA0), AS3(As + (wv << 9)),        16, 0, 0);
        __builtin_amdgcn_global_load_lds(AS1(gA1), AS3(As + 2048 + (wv << 9)), 16, 0, 0);
        __builtin_amdgcn_global_load_lds(AS1(gB0), AS3(Bs + (wv << 9)),        16, 0, 0);
        __builtin_amdgcn_global_load_lds(AS1(gB1), AS3(Bs + 2048 + (wv << 9)), 16, 0, 0);
        gA0 += 32; gA1 += 32; gB0 += 32; gB1 += 32;
        __syncthreads();

        bf16x8 af[4], bf[4];
#pragma unroll
        for (int t = 0; t < 4; ++t) {
            af[t] = *(const bf16x8*)(As + caddr[t]);
            bf[t] = *(const bf16x8*)(Bs + baddr[t]);
        }
#pragma unroll
        for (int i = 0; i < 4; ++i)
#pragma unroll
            for (int j = 0; j < 4; ++j)
                acc[i][j] = __builtin_amdgcn_mfma_f32_16x16x32_bf16(
                    af[i], bf[j], acc[i][j], 0, 0, 0);
        __syncthreads();
    }

    const int col0 = bn + wn + fm;
    const int row0 = bm + wm + (fq << 2);
    float* Cf = (float*)Cv;
    short* Cb = (short*)Cv;
#pragma unroll
    for (int j = 0; j < 4; ++j) {
        const int colg = col0 + (j << 4);
        const float bb = bias[colg];
#pragma unroll
        for (int i = 0; i < 4; ++i) {
#pragma unroll
            for (int r = 0; r < 4; ++r) {
                const int rowg = row0 + (i << 4) + r;
                float v = acc[i][j][r] + bb;
                if (ACT) v = v / (1.f + __expf(-v));
                const size_t off = (size_t)rowg * N + colg;
                if (RES) v += R[off];
                if (OUTM == 1) Cb[off] = f2bf(v);
                else           Cf[off] = v;
            }
        }
    }
}

// ---------------------------------------------------------------------------
// QKV GEMM, 128x64 tile (768 blocks). N=1536 fixed.
// Q,K -> QKb [M][1024]; V -> Vt [B*H][64][T] (transposed scatter).
// ---------------------------------------------------------------------------
__global__ __launch_bounds__(256) void qkv64_k(
    const short* __restrict__ A, const short* __restrict__ Wt,
    const float* __restrict__ bias, short* __restrict__ QKb,
    short* __restrict__ VtOut)
{
    const int K = D_;
    __shared__ short As[128 * 32];
    __shared__ short Bs[64 * 32];
    const int tid  = threadIdx.x;
    const int lane = tid & 63, wv = tid >> 6;
    const int bm = blockIdx.y << 7, bn = blockIdx.x << 6;
    const int wm = (wv & 1) << 6, wn = (wv >> 1) << 5;

    const int c0 = (wv << 6) + lane;
    const int m0 = c0 >> 2, q0 = (c0 & 3) ^ ((m0 >> 1) & 3);
    const int c1 = 256 + c0;
    const int m1 = c1 >> 2, q1 = (c1 & 3) ^ ((m1 >> 1) & 3);

    const short* gA0 = A  + (size_t)(bm + m0) * K + (q0 << 3);
    const short* gA1 = A  + (size_t)(bm + m1) * K + (q1 << 3);
    const short* gB0 = Wt + (size_t)(bn + m0) * K + (q0 << 3);

    f32x4 acc[4][2];
#pragma unroll
    for (int i = 0; i < 4; ++i)
#pragma unroll
        for (int j = 0; j < 2; ++j)
            acc[i][j] = (f32x4){0.f, 0.f, 0.f, 0.f};

    const int fm = lane & 15, fq = lane >> 4;
    int caddr[4], baddr[2];
#pragma unroll
    for (int t = 0; t < 4; ++t) {
        const int rowA = wm + (t << 4) + fm;
        caddr[t] = ((rowA << 2) + (fq ^ ((rowA >> 1) & 3))) << 3;
    }
#pragma unroll
    for (int t = 0; t < 2; ++t) {
        const int rowB = wn + (t << 4) + fm;
        baddr[t] = ((rowB << 2) + (fq ^ ((rowB >> 1) & 3))) << 3;
    }

    for (int k0 = 0; k0 < K; k0 += 32) {
        __builtin_amdgcn_global_load_lds(AS1(gA0), AS3(As + (wv << 9)),        16, 0, 0);
        __builtin_amdgcn_global_load_lds(AS1(gA1), AS3(As + 2048 + (wv << 9)), 16, 0, 0);
        __builtin_amdgcn_global_load_lds(AS1(gB0), AS3(Bs + (wv << 9)),        16, 0, 0);
        gA0 += 32; gA1 += 32; gB0 += 32;
        __syncthreads();

        bf16x8 af[4], bf[2];
#pragma unroll
        for (int t = 0; t < 4; ++t) af[t] = *(const bf16x8*)(As + caddr[t]);
#pragma unroll
        for (int t = 0; t < 2; ++t) bf[t] = *(const bf16x8*)(Bs + baddr[t]);
#pragma unroll
        for (int i = 0; i < 4; ++i)
#pragma unroll
            for (int j = 0; j < 2; ++j)
                acc[i][j] = __builtin_amdgcn_mfma_f32_16x16x32_bf16(
                    af[i], bf[j], acc[i][j], 0, 0, 0);
        __syncthreads();
    }

    const int col0 = bn + wn + fm;
    const int row0 = bm + wm + (fq << 2);
#pragma unroll
    for (int j = 0; j < 2; ++j) {
        const int colg = col0 + (j << 4);
        const float bb = bias[colg];
#pragma unroll
        for (int i = 0; i < 4; ++i) {
#pragma unroll
            for (int r = 0; r < 4; ++r) {
                const int rowg = row0 + (i << 4) + r;
                const float v = acc[i][j][r] + bb;
                if (colg < 1024) {
                    QKb[(size_t)rowg * 1024 + colg] = f2bf(v);
                } else {
                    const int da = colg - 1024;
                    const int hh = da >> 6, dd = da & 63;
                    const int bb2 = rowg >> 10, tt = rowg & 1023;
                    VtOut[((size_t)(bb2 * H_ + hh) * 64 + dd) * T_ + tt] = f2bf(v);
                }
            }
        }
    }
}

// ---------------------------------------------------------------------------
// MFMA flash attention v3.2 (unchanged from round 9): fixed-max softmax,
// split-K x2, MFMA row-sum, u8 bias LDS tile. bf16 O-partials.
// ---------------------------------------------------------------------------
__global__ __launch_bounds__(256) void flash_k(
    const short* __restrict__ QKb, const short* __restrict__ Vt,
    const unsigned char* __restrict__ biasT8, short* __restrict__ OpartB,
    float* __restrict__ Lpart)
{
    const int tid = threadIdx.x;
    const int bx = blockIdx.x;
    const int it = bx >> 1, split = bx & 1;
    const int i0 = it << 6;
    const int h  = blockIdx.y;
    const int b  = blockIdx.z;
    const int lane = tid & 63, w = tid >> 6;
    const int fm = lane & 15, q = lane >> 4;

    __shared__ short Ks[4096];
    __shared__ short Vs[4096];
    __shared__ unsigned char Bsh8[4096];
    __shared__ short Ps[64][72];

    const short* qp = QKb + (size_t)(b * T_ + i0 + (w << 4) + fm) * 1024 + (h << 6) + (q << 3);
    const bf16x8 aq0 = *(const bf16x8*)(qp);
    const bf16x8 aq1 = *(const bf16x8*)(qp + 32);

    const int s0 = (w << 6) + lane, r0 = s0 >> 3, cc0 = (s0 & 7) ^ (r0 & 7);
    const int s1 = 256 + s0,        r1 = s1 >> 3, cc1 = (s1 & 7) ^ (r1 & 7);
    const short* gK0 = QKb + (size_t)(b * T_ + r0) * 1024 + 512 + (h << 6) + (cc0 << 3);
    const short* gK1 = QKb + (size_t)(b * T_ + r1) * 1024 + 512 + (h << 6) + (cc1 << 3);
    const short* gV0 = Vt + ((size_t)((b * H_ + h) << 6) + r0) * T_ + (cc0 << 3);
    const short* gV1 = Vt + ((size_t)((b * H_ + h) << 6) + r1) * T_ + (cc1 << 3);
    const int br = s0 >> 2, bc = (s0 & 3) ^ (br & 3);
    const unsigned char* gB0 = biasT8 +
        ((size_t)(b * H_ + h) * T_ + i0 + br) * T_ + (bc << 4);

    int fAddr[4][2];
#pragma unroll
    for (int t = 0; t < 4; ++t) {
        const int row = (t << 4) + fm;
#pragma unroll
        for (int ks = 0; ks < 2; ++ks)
            fAddr[t][ks] = (row << 6) + (((q + (ks << 2)) ^ (row & 7)) << 3);
    }

    int bAddr[4][4];
#pragma unroll
    for (int r = 0; r < 4; ++r) {
        const int rowL = (w << 4) + (q << 2) + r;
#pragma unroll
        for (int jt = 0; jt < 4; ++jt)
            bAddr[r][jt] = (rowL << 6) + (((jt ^ (rowL & 3))) << 4) + fm;
    }

    const short oneb = 0x3F80;
    const bf16x8 ones = {oneb, oneb, oneb, oneb, oneb, oneb, oneb, oneb};

    f32x4 accO[4];
#pragma unroll
    for (int dt = 0; dt < 4; ++dt) accO[dt] = (f32x4){0.f, 0.f, 0.f, 0.f};
    f32x4 accL = (f32x4){0.f, 0.f, 0.f, 0.f};

    const int irow = b * T_ + i0 + (w << 4) + (q << 2);
    short* psW = &Ps[(w << 4) + (q << 2)][fm];
    const short* psR = &Ps[(w << 4) + fm][q << 3];

    const int jbeg = split << 9, jend = jbeg + 512;
    for (int j0 = jbeg; j0 < jend; j0 += 64) {
        __syncthreads();
        __builtin_amdgcn_global_load_lds(AS1(gK0 + (size_t)j0 * 1024), AS3(Ks + (s0 << 3)), 16, 0, 0);
        __builtin_amdgcn_global_load_lds(AS1(gK1 + (size_t)j0 * 1024), AS3(Ks + (s1 << 3)), 16, 0, 0);
        __builtin_amdgcn_global_load_lds(AS1(gV0 + j0), AS3(Vs + (s0 << 3)), 16, 0, 0);
        __builtin_amdgcn_global_load_lds(AS1(gV1 + j0), AS3(Vs + (s1 << 3)), 16, 0, 0);
        __builtin_amdgcn_global_load_lds(AS1(gB0 + j0), AS3(Bsh8 + (s0 << 4)), 16, 0, 0);
        __syncthreads();

        f32x4 s[4];
#pragma unroll
        for (int jt = 0; jt < 4; ++jt) s[jt] = (f32x4){0.f, 0.f, 0.f, 0.f};
#pragma unroll
        for (int jt = 0; jt < 4; ++jt) {
            const bf16x8 k0 = *(const bf16x8*)(Ks + fAddr[jt][0]);
            const bf16x8 k1 = *(const bf16x8*)(Ks + fAddr[jt][1]);
            s[jt] = __builtin_amdgcn_mfma_f32_16x16x32_bf16(aq0, k0, s[jt], 0, 0, 0);
            s[jt] = __builtin_amdgcn_mfma_f32_16x16x32_bf16(aq1, k1, s[jt], 0, 0, 0);
        }

#pragma unroll
        for (int r = 0; r < 4; ++r)
#pragma unroll
            for (int jt = 0; jt < 4; ++jt) {
                const float q8 = (float)Bsh8[bAddr[r][jt]];
                const float bb = fmaf(q8, 1.f / 255.f, -0.5f);
                const float p = __builtin_amdgcn_exp2f(fmaf(s[jt][r], CL2E_, bb));
                psW[(size_t)r * 72 + (jt << 4)] = f2bf(p);
            }

#pragma unroll
        for (int ks = 0; ks < 2; ++ks) {
            const bf16x8 ap = *(const bf16x8*)(psR + (ks << 5));
            accL = __builtin_amdgcn_mfma_f32_16x16x32_bf16(ap, ones, accL, 0, 0, 0);
#pragma unroll
            for (int dt = 0; dt < 4; ++dt) {
                const bf16x8 bv = *(const bf16x8*)(Vs + fAddr[dt][ks]);
                accO[dt] = __builtin_amdgcn_mfma_f32_16x16x32_bf16(ap, bv, accO[dt], 0, 0, 0);
            }
        }
    }

    short* obase = OpartB + (size_t)split * B_ * T_ * D_;
#pragma unroll
    for (int r = 0; r < 4; ++r) {
        short* op = obase + (size_t)(irow + r) * D_ + (h << 6) + fm;
#pragma unroll
        for (int dt = 0; dt < 4; ++dt)
            op[dt << 4] = f2bf(accO[dt][r]);
    }
    if (fm == 0) {
#pragma unroll
        for (int r = 0; r < 4; ++r)
            Lpart[(size_t)split * B_ * T_ * H_ + (size_t)(irow + r) * H_ + h] = accL[r];
    }
}

// ---------------------------------------------------------------------------
// O-projection with FUSED split-K combine: A[m][k] = (O0+O1)*(1/(l0+l1)),
// built in VGPRs and staged to LDS via ds_write_b128 with the same XOR chunk
// mapping the fragment reads expect. B via global_load_lds. 128x64 tile,
// fp32 out + residual. head = k0>>6 is uniform per K-step.
// ---------------------------------------------------------------------------
__global__ __launch_bounds__(256) void oproj_k(
    const short* __restrict__ O0, const short* __restrict__ O1,
    const float* __restrict__ L0, const float* __restrict__ L1,
    const short* __restrict__ Wt, const float* __restrict__ bias,
    const float* __restrict__ R, float* __restrict__ C)
{
    const int K = D_, N = D_;
    __shared__ short As[128 * 32];
    __shared__ short Bs[64 * 32];
    const int tid  = threadIdx.x;
    const int lane = tid & 63, wv = tid >> 6;
    const int bm = blockIdx.y << 7, bn = blockIdx.x << 6;
    const int wm = (wv & 1) << 6, wn = (wv >> 1) << 5;

    const int c0 = (wv << 6) + lane;
    const int m0 = c0 >> 2, q0 = (c0 & 3) ^ ((m0 >> 1) & 3);
    const int c1 = 256 + c0;
    const int m1 = c1 >> 2, q1 = (c1 & 3) ^ ((m1 >> 1) & 3);

    // A sources (VGPR path)
    const short* gA00 = O0 + (size_t)(bm + m0) * D_ + (q0 << 3);
    const short* gA01 = O1 + (size_t)(bm + m0) * D_ + (q0 << 3);
    const short* gA10 = O0 + (size_t)(bm + m1) * D_ + (q1 << 3);
    const short* gA11 = O1 + (size_t)(bm + m1) * D_ + (q1 << 3);
    const float* lp00 = L0 + (size_t)(bm + m0) * H_;
    const float* lp01 = L1 + (size_t)(bm + m0) * H_;
    const float* lp10 = L0 + (size_t)(bm + m1) * H_;
    const float* lp11 = L1 + (size_t)(bm + m1) * H_;
    // B (async path)
    const short* gB0 = Wt + (size_t)(bn + m0) * K + (q0 << 3);

    f32x4 acc[4][2];
#pragma unroll
    for (int i = 0; i < 4; ++i)
#pragma unroll
        for (int j = 0; j < 2; ++j)
            acc[i][j] = (f32x4){0.f, 0.f, 0.f, 0.f};

    const int fm = lane & 15, fq = lane >> 4;
    int caddr[4], baddr[2];
#pragma unroll
    for (int t = 0; t < 4; ++t) {
        const int rowA = wm + (t << 4) + fm;
        caddr[t] = ((rowA << 2) + (fq ^ ((rowA >> 1) & 3))) << 3;
    }
#pragma unroll
    for (int t = 0; t < 2; ++t) {
        const int rowB = wn + (t << 4) + fm;
        baddr[t] = ((rowB << 2) + (fq ^ ((rowB >> 1) & 3))) << 3;
    }

    for (int k0 = 0; k0 < K; k0 += 32) {
        const int h = k0 >> 6;   // uniform over the 32-wide K window
        // build A chunks in VGPRs (combine + normalize)
        const bf16x8 xa0 = *(const bf16x8*)(gA00 + k0);
        const bf16x8 xb0 = *(const bf16x8*)(gA01 + k0);
        const bf16x8 xa1 = *(const bf16x8*)(gA10 + k0);
        const bf16x8 xb1 = *(const bf16x8*)(gA11 + k0);
        const float inv0 = 1.f / (lp00[h] + lp01[h]);
        const float inv1 = 1.f / (lp10[h] + lp11[h]);
        bf16x8 p0, p1;
#pragma unroll
        for (int i = 0; i < 8; ++i) {
            p0[i] = f2bf((bf2f(xa0[i]) + bf2f(xb0[i])) * inv0);
            p1[i] = f2bf((bf2f(xa1[i]) + bf2f(xb1[i])) * inv1);
        }
        // B async stage
        __builtin_amdgcn_global_load_lds(AS1(gB0), AS3(Bs + (wv << 9)), 16, 0, 0);
        gB0 += 32;
        // A LDS stage (after all prior frag reads: guarded by loop-end barrier)
        *(bf16x8*)(As + (c0 << 3)) = p0;
        *(bf16x8*)(As + (c1 << 3)) = p1;
        __syncthreads();

        bf16x8 af[4], bf[2];
#pragma unroll
        for (int t = 0; t < 4; ++t) af[t] = *(const bf16x8*)(As + caddr[t]);
#pragma unroll
        for (int t = 0; t < 2; ++t) bf[t] = *(const bf16x8*)(Bs + baddr[t]);
#pragma unroll
        for (int i = 0; i < 4; ++i)
#pragma unroll
            for (int j = 0; j < 2; ++j)
                acc[i][j] = __builtin_amdgcn_mfma_f32_16x16x32_bf16(
                    af[i], bf[j], acc[i][j], 0, 0, 0);
        __syncthreads();
    }

    const int col0 = bn + wn + fm;
    const int row0 = bm + wm + (fq << 2);
#pragma unroll
    for (int j = 0; j < 2; ++j) {
        const int colg = col0 + (j << 4);
        const float bb = bias[colg];
#pragma unroll
        for (int i = 0; i < 4; ++i) {
#pragma unroll
            for (int r = 0; r < 4; ++r) {
                const int rowg = row0 + (i << 4) + r;
                const size_t off = (size_t)rowg * N + colg;
                C[off] = acc[i][j][r] + bb + R[off];
            }
        }
    }
}

// ---------------------------------------------------------------------------
// bf16 MFMA GEMM, 128x64 tile (N=512: 256 blocks). fp32 out + residual.
// ---------------------------------------------------------------------------
__global__ __launch_bounds__(256) void mm64_k(
    const short* __restrict__ A, const short* __restrict__ Wt,
    const float* __restrict__ bias, const float* __restrict__ R,
    float* __restrict__ C, int M, int N, int K)
{
    __shared__ short As[128 * 32];
    __shared__ short Bs[64 * 32];
    const int tid  = threadIdx.x;
    const int lane = tid & 63, wv = tid >> 6;
    const int bm = blockIdx.y << 7, bn = blockIdx.x << 6;
    const int wm = (wv & 1) << 6, wn = (wv >> 1) << 5;

    const int c0 = (wv << 6) + lane;
    const int m0 = c0 >> 2, q0 = (c0 & 3) ^ ((m0 >> 1) & 3);
    const int c1 = 256 + c0;
    const int m1 = c1 >> 2, q1 = (c1 & 3) ^ ((m1 >> 1) & 3);

    const short* gA0 = A  + (size_t)(bm + m0) * K + (q0 << 3);
    const short* gA1 = A  + (size_t)(bm + m1) * K + (q1 << 3);
    const short* gB0 = Wt + (size_t)(bn + m0) * K + (q0 << 3);

    f32x4 acc[4][2];
#pragma unroll
    for (int i = 0; i < 4; ++i)
#pragma unroll
        for (int j = 0; j < 2; ++j)
            acc[i][j] = (f32x4){0.f, 0.f, 0.f, 0.f};

    const int fm = lane & 15, fq = lane >> 4;
    int caddr[4], baddr[2];
#pragma unroll
    for (int t = 0; t < 4; ++t) {
        const int rowA = wm + (t << 4) + fm;
        caddr[t] = ((rowA << 2) + (fq ^ ((rowA >> 1) & 3))) << 3;
    }
#pragma unroll
    for (int t = 0; t < 2; ++t) {
        const int rowB = wn + (t << 4) + fm;
        baddr[t] = ((rowB << 2) + (fq ^ ((rowB >> 1) & 3))) << 3;
    }

    for (int k0 = 0; k0 < K; k0 += 32) {
        __builtin_amdgcn_global_load_lds(AS1(gA0), AS3(As + (wv << 9)),        16, 0, 0);
        __builtin_amdgcn_global_load_lds(AS1(gA1), AS3(As + 2048 + (wv << 9)), 16, 0, 0);
        __builtin_amdgcn_global_load_lds(AS1(gB0), AS3(Bs + (wv << 9)),        16, 0, 0);
        gA0 += 32; gA1 += 32; gB0 += 32;
        __syncthreads();

        bf16x8 af[4], bf[2];
#pragma unroll
        for (int t = 0; t < 4; ++t) af[t] = *(const bf16x8*)(As + caddr[t]);
#pragma unroll
        for (int t = 0; t < 2; ++t) bf[t] = *(const bf16x8*)(Bs + baddr[t]);
#pragma unroll
        for (int i = 0; i < 4; ++i)
#pragma unroll
            for (int j = 0; j < 2; ++j)
                acc[i][j] = __builtin_amdgcn_mfma_f32_16x16x32_bf16(
                    af[i], bf[j], acc[i][j], 0, 0, 0);
        __syncthreads();
    }

    const int col0 = bn + wn + fm;
    const int row0 = bm + wm + (fq << 2);
#pragma unroll
    for (int j = 0; j < 2; ++j) {
        const int colg = col0 + (j << 4);
        const float bb = bias[colg];
#pragma unroll
        for (int i = 0; i < 4; ++i) {
#pragma unroll
            for (int r = 0; r < 4; ++r) {
                const int rowg = row0 + (i << 4) + r;
                const size_t off = (size_t)rowg * N + colg;
                C[off] = acc[i][j][r] + bb + R[off];
            }
        }
    }
}

// ---------------------------------------------------------------------------
extern "C" void kernel_launch(void* const* d_in, const int* in_sizes, int n_in,
                              void* d_out, int out_size, void* d_ws, size_t ws_size,
                              hipStream_t stream)
{
    (void)in_sizes; (void)n_in; (void)out_size; (void)ws_size;

    const float* nf   = (const float*)d_in[0];
    const float* cent = (const float*)d_in[1];
    const int*   et   = (const int*)  d_in[2];
    const int*   sp   = (const int*)  d_in[3];
    const float* nW   = (const float*)d_in[4];
    const float* nb   = (const float*)d_in[5];
    const float* cW   = (const float*)d_in[6];
    const float* cb   = (const float*)d_in[7];
    const float* ee   = (const float*)d_in[8];
    const float* de   = (const float*)d_in[9];
    const float* ln1w = (const float*)d_in[10];
    const float* ln1b = (const float*)d_in[11];
    const float* qW   = (const float*)d_in[12];
    const float* qb   = (const float*)d_in[13];
    const float* kW   = (const float*)d_in[14];
    const float* kb   = (const float*)d_in[15];
    const float* vW   = (const float*)d_in[16];
    const float* vb   = (const float*)d_in[17];
    const float* oW   = (const float*)d_in[18];
    const float* ob   = (const float*)d_in[19];
    const float* ln2w = (const float*)d_in[20];
    const float* ln2b = (const float*)d_in[21];
    const float* f1W  = (const float*)d_in[22];
    const float* f1b  = (const float*)d_in[23];
    const float* f2W  = (const float*)d_in[24];
    const float* f2b  = (const float*)d_in[25];

    const int M = B_ * T_;                          // 4096
    char* p = (char*)d_ws;
    float* Hbuf  = (float*)p;  p += (size_t)M * D_ * 4;                    // 8 MB
    short* QKb   = (short*)p;  p += (size_t)M * 1024 * 2;                  // 8 MB
    short* Vt    = (short*)p;  p += (size_t)B_ * H_ * 64 * T_ * 2;         // 4 MB
    float* biasf = (float*)p;  p += (size_t)L_ * 3 * D_ * 4;               // 24 KB
    short* Xbuf  = (short*)p;  p += (size_t)M * D_ * 2;                    // 4 MB
    short* FF    = (short*)p;  p += (size_t)M * DFF_ * 2;                  // 16 MB
    unsigned char* biasT8 = (unsigned char*)p; p += (size_t)B_ * H_ * T_ * T_; // 33.5 MB
    short* WqkvT = (short*)p;  p += (size_t)L_ * 3 * D_ * D_ * 2;
    short* WoT   = (short*)p;  p += (size_t)L_ * D_ * D_ * 2;
    short* Wf1T  = (short*)p;  p += (size_t)L_ * DFF_ * D_ * 2;
    short* Wf2T  = (short*)p;  p += (size_t)L_ * D_ * DFF_ * 2;
    short* nfb   = (short*)p;  p += (size_t)M * F_ * 2;                    // 1 MB
    short* nWt   = (short*)p;  p += (size_t)D_ * F_ * 2;                   // 128 KB
    short* OpartB = (short*)p; p += (size_t)2 * M * D_ * 2;                // 8 MB
    float* Lpart = (float*)p;  p += (size_t)2 * M * H_ * 4;                // 256 KB

    float* out = (float*)d_out;

    // ---- prep (2 dispatches)
    prep_all_k<<<dim3(16984), dim3(256), 0, stream>>>(
        qW, kW, vW, oW, f1W, f2W, nW, WqkvT, WoT, Wf1T, Wf2T, nWt,
        et, sp, ee, de, biasT8, nf, nfb, qb, kb, vb, biasf);
    embed_mm_k<<<dim3(D_ / 64, M / 128), dim3(256), 0, stream>>>(
        nfb, nWt, nb, cb, cW, cent, Hbuf);

    const dim3 blk(256);
    const dim3 gQKV(3 * D_ / 64, M / 128);    // (24, 32) = 768 blocks
    const dim3 gO64(D_ / 64,     M / 128);    // (8, 32)  = 256 blocks
    const dim3 gF1 (DFF_ / 128,  M / 128);    // (16, 32) = 512 blocks
    const dim3 gAttn(2 * T_ / 64, H_, B_);    // (32, 8, 4) = 1024 blocks

    for (int l = 0; l < L_; ++l) {
        const size_t bOff  = (size_t)l * D_;
        const size_t b1Off = (size_t)l * DFF_;

        ln_k<<<dim3(M), blk, 0, stream>>>(Hbuf, ln1w + bOff, ln1b + bOff, Xbuf);

        qkv64_k<<<gQKV, blk, 0, stream>>>(
            Xbuf, WqkvT + (size_t)l * 3 * D_ * D_, biasf + (size_t)l * 3 * D_,
            QKb, Vt);

        flash_k<<<gAttn, blk, 0, stream>>>(QKb, Vt, biasT8, OpartB, Lpart);

        oproj_k<<<gO64, blk, 0, stream>>>(
            OpartB, OpartB + (size_t)M * D_, Lpart, Lpart + (size_t)M * H_,
            WoT + (size_t)l * D_ * D_, ob + bOff, Hbuf, Hbuf);

        ln_k<<<dim3(M), blk, 0, stream>>>(Hbuf, ln2w + bOff, ln2b + bOff, Xbuf);

        mm_k<1, 1, 0><<<gF1, blk, 0, stream>>>(
            Xbuf, Wf1T + (size_t)l * DFF_ * D_, f1b + b1Off, nullptr, FF, M, DFF_, D_);

        float* cdst = (l == L_ - 1) ? out : Hbuf;
        mm64_k<<<gO64, blk, 0, stream>>>(
            FF, Wf2T + (size_t)l * D_ * DFF_, f2b + bOff, Hbuf, cdst, M, D_, DFF_);
    }
}